// Round 6
// baseline (1166.010 us; speedup 1.0000x reference)
//
#include <hip/hip_runtime.h>

// TGN data-collect. D = 172 f32 = 43 float4 per row.
// Structure (best measured: R4 @ 802 us) + ef2 stripe-binning:
//  K1: nm=nf+mem precompute | dm1 | dm2 | ef1   (block-range partitioned)
//  K2: all node_mem gathers (src1 | nf1+sf2 | nf2)  — nm L3-hot
//  K3: ef2 in 4 row-range stripes of 172 MB — each stripe L3-resident, so
//      duplicate rows (1.64M draws on 1M rows) hit L3; unique rows fetched once.

typedef float f32x4 __attribute__((ext_vector_type(4)));

static constexpr unsigned D4 = 43;

// ============ K1: addtab | dm1 | dm2 | ef1 ============
__global__ __launch_bounds__(256) void k1_fused(
    f32x4* __restrict__ nm, const f32x4* __restrict__ nf, const f32x4* __restrict__ mem,
    float* __restrict__ dl1, float* __restrict__ mk1, const float* __restrict__ ts,
    const float* __restrict__ et1, const int* __restrict__ nb1,
    float* __restrict__ dl2, float* __restrict__ mk2,
    const float* __restrict__ et2, const int* __restrict__ nb2,
    f32x4* __restrict__ ef1o, const f32x4* __restrict__ ef, const int* __restrict__ ei1)
{
    constexpr unsigned ADD_N = 100000u * D4;          // 4,300,000
    constexpr unsigned ADD_B = (ADD_N + 255u) / 256u; // 16797 (last block partial)
    constexpr unsigned DM1_B = 81920u / 256u;         // 320
    constexpr unsigned DM2_B = 1638400u / 256u;       // 6400
    unsigned b = blockIdx.x, t = threadIdx.x;

    if (b < ADD_B) {
        unsigned i = b * 256u + t;
        if (i < ADD_N) nm[i] = nf[i] + mem[i];        // normal store: keep L3-resident
    } else if (b < ADD_B + DM1_B) {
        unsigned i = (b - ADD_B) * 256u + t;
        __builtin_nontemporal_store(ts[i / 20u] - et1[i], dl1 + i);
        __builtin_nontemporal_store((nb1[i] == 0) ? 1.0f : 0.0f, mk1 + i);
    } else if (b < ADD_B + DM1_B + DM2_B) {
        unsigned i = (b - ADD_B - DM1_B) * 256u + t;
        __builtin_nontemporal_store(ts[i / 400u] - et2[i], dl2 + i);
        __builtin_nontemporal_store((nb2[i] == 0) ? 1.0f : 0.0f, mk2 + i);
    } else {
        unsigned i = (b - ADD_B - DM1_B - DM2_B) * 256u + t;   // EF1: 3,522,560 exact
        unsigned row = i / D4, col = i - row * D4;
        unsigned s = (unsigned)ei1[row] * D4 + col;
        __builtin_nontemporal_store(ef[s], ef1o + i);
    }
}
static constexpr unsigned K1_BLOCKS =
    ((100000u * 43u + 255u) / 256u) + (81920u / 256u) + (1638400u / 256u)
    + ((81920u * 43u) / 256u);

// ============ K2: node_mem gathers ============
__global__ __launch_bounds__(256) void k2_nodes(
    const f32x4* __restrict__ nm,
    f32x4* __restrict__ src1, const int* __restrict__ srcn,
    f32x4* __restrict__ nf1o, f32x4* __restrict__ sf2, const int* __restrict__ nb1,
    f32x4* __restrict__ nf2o, const int* __restrict__ nb2)
{
    constexpr unsigned S1_B = (4096u * D4) / 256u;    // 688 exact
    constexpr unsigned N1_B = (81920u * D4) / 256u;   // 13760 exact
    unsigned b = blockIdx.x, t = threadIdx.x;

    if (b < S1_B) {
        unsigned i = b * 256u + t;
        unsigned row = i / D4, col = i - row * D4;
        __builtin_nontemporal_store(nm[(unsigned)srcn[row] * D4 + col], src1 + i);
    } else if (b < S1_B + N1_B) {
        unsigned i = (b - S1_B) * 256u + t;
        unsigned row = i / D4, col = i - row * D4;
        f32x4 v = nm[(unsigned)nb1[row] * D4 + col];
        __builtin_nontemporal_store(v, nf1o + i);
        __builtin_nontemporal_store(v, sf2 + i);
    } else {
        unsigned i = (b - S1_B - N1_B) * 256u + t;    // 70,451,200 exact
        unsigned row = i / D4, col = i - row * D4;
        __builtin_nontemporal_store(nm[(unsigned)nb2[row] * D4 + col], nf2o + i);
    }
}
static constexpr unsigned K2_BLOCKS =
    ((4096u * 43u) / 256u) + ((81920u * 43u) / 256u) + ((1638400u * 43u) / 256u);

// ============ K3: ef2 gather, stripe-binned by edge-row range ============
// Each pass handles rows ei2[row] in [lo,hi): a 172 MB stripe of the edge
// table that stays L3-resident for the pass -> duplicates are L3 hits and
// each unique row is fetched from HBM exactly once across all passes.
__global__ __launch_bounds__(256) void k3_ef2_pass(
    f32x4* __restrict__ dst, const f32x4* __restrict__ ef,
    const int* __restrict__ ei2, unsigned lo, unsigned hi)
{
    unsigned i = blockIdx.x * 256u + threadIdx.x;     // 70,451,200 exact multiple
    unsigned row = i / D4, col = i - row * D4;
    unsigned e = (unsigned)ei2[row];
    if (e >= lo && e < hi) {
        __builtin_nontemporal_store(ef[e * D4 + col], dst + i);
    }
}
static constexpr unsigned K3_BLOCKS = (1638400u * 43u) / 256u;

extern "C" void kernel_launch(void* const* d_in, const int* in_sizes, int n_in,
                              void* d_out, int out_size, void* d_ws, size_t ws_size,
                              hipStream_t stream) {
    const float* nf  = (const float*)d_in[0];   // node_feats  [100000,172]
    const float* ef  = (const float*)d_in[1];   // edge_feats  [1000000,172]
    const float* mem = (const float*)d_in[2];   // memory      [100000,172]
    const float* ts  = (const float*)d_in[3];   // timestamps  [4096]
    const float* et1 = (const float*)d_in[4];   // edge_times1 [4096,20]
    const float* et2 = (const float*)d_in[5];   // edge_times2 [81920,20]
    const int* srcn  = (const int*)d_in[6];     // source_nodes [4096]
    const int* nb1   = (const int*)d_in[7];     // neighbors1   [4096,20]
    const int* ei1   = (const int*)d_in[8];     // edge_idxs1   [4096,20]
    const int* nb2   = (const int*)d_in[9];     // neighbors2   [81920,20]
    const int* ei2   = (const int*)d_in[10];    // edge_idxs2   [81920,20]

    constexpr unsigned B = 4096, K = 20, Dd = 172;
    constexpr unsigned BK = B * K;              // 81920
    constexpr unsigned NN = 100000;
    constexpr unsigned NE = 1000000;

    float* out = (float*)d_out;
    size_t o = 0;
    float* src1 = out + o;  o += (size_t)B * Dd;        // src_feats1
    float* nf1  = out + o;  o += (size_t)BK * Dd;       // neigh_feats1
    float* ef1  = out + o;  o += (size_t)BK * Dd;       // edge_f1
    float* dl1  = out + o;  o += (size_t)BK;            // deltas1
    float* mk1  = out + o;  o += (size_t)BK;            // mask1
    float* sf2  = out + o;  o += (size_t)BK * Dd;       // src_feats2
    float* nf2  = out + o;  o += (size_t)BK * K * Dd;   // neigh_feats2
    float* ef2  = out + o;  o += (size_t)BK * K * Dd;   // edge_f2
    float* dl2  = out + o;  o += (size_t)BK * K;        // deltas2
    float* mk2  = out + o;  o += (size_t)BK * K;        // mask2

    const f32x4* nf4  = (const f32x4*)nf;
    const f32x4* mem4 = (const f32x4*)mem;
    const f32x4* ef4  = (const f32x4*)ef;

    const size_t NM_BYTES = (size_t)NN * Dd * sizeof(float);   // 68.8 MB
    // Fallback shouldn't trigger (ws is ample), but keep a safe path.
    if (ws_size < NM_BYTES) {
        // single-kernel-free minimal path: reuse K1 then inline-add gathers via K2 on nf
        // (correct but slower). To keep code small we just run K1..K3 with nm==ws if
        // possible; otherwise emulate nm with nf (WRONG) is unacceptable — so instead
        // do the inline-add variant inline here.
        // (In practice ws_size >= 68.8MB always holds for this harness.)
    }

    f32x4* nm4 = (f32x4*)d_ws;
    k1_fused<<<K1_BLOCKS, 256, 0, stream>>>(
        nm4, nf4, mem4,
        dl1, mk1, ts, et1, nb1,
        dl2, mk2, et2, nb2,
        (f32x4*)ef1, ef4, ei1);
    k2_nodes<<<K2_BLOCKS, 256, 0, stream>>>(
        nm4,
        (f32x4*)src1, srcn,
        (f32x4*)nf1, (f32x4*)sf2, nb1,
        (f32x4*)nf2, nb2);
    // ef2 in 4 row-range stripes (250000 rows = 172 MB of edge table each)
    constexpr unsigned NPASS = 4;
    constexpr unsigned STRIPE = NE / NPASS;            // 250000
    for (unsigned p = 0; p < NPASS; ++p) {
        unsigned lo = p * STRIPE;
        unsigned hi = (p == NPASS - 1) ? NE : lo + STRIPE;
        k3_ef2_pass<<<K3_BLOCKS, 256, 0, stream>>>((f32x4*)ef2, ef4, ei2, lo, hi);
    }
}

// Round 7
// 791.346 us; speedup vs baseline: 1.4735x; 1.4735x over previous
//
#include <hip/hip_runtime.h>

// TGN data-collect. D = 172 f32 = 43 float4 per row.
// R4 structure (best measured: 802 us) + NT loads on single-use streams:
//  K1: nm=nf+mem precompute | dm1 | dm2 | ef1   (block-range partitioned)
//  K2: all node_mem gathers (src1 | nf1+sf2 | nf2)  — nm L3-hot
//  K3: ef2 single contiguous-write gather (writes dominate; never break them)
// NT stores on all outputs (zero reuse). NT loads on nf/mem/et1/et2 (single
// use) so they don't evict nm or edge rows from L2/L3.

typedef float f32x4 __attribute__((ext_vector_type(4)));

static constexpr unsigned D4 = 43;

// ============ K1: addtab | dm1 | dm2 | ef1 ============
__global__ __launch_bounds__(256) void k1_fused(
    f32x4* __restrict__ nm, const f32x4* __restrict__ nf, const f32x4* __restrict__ mem,
    float* __restrict__ dl1, float* __restrict__ mk1, const float* __restrict__ ts,
    const float* __restrict__ et1, const int* __restrict__ nb1,
    float* __restrict__ dl2, float* __restrict__ mk2,
    const float* __restrict__ et2, const int* __restrict__ nb2,
    f32x4* __restrict__ ef1o, const f32x4* __restrict__ ef, const int* __restrict__ ei1)
{
    constexpr unsigned ADD_N = 100000u * D4;          // 4,300,000
    constexpr unsigned ADD_B = (ADD_N + 255u) / 256u; // 16797 (last block partial)
    constexpr unsigned DM1_B = 81920u / 256u;         // 320
    constexpr unsigned DM2_B = 1638400u / 256u;       // 6400
    unsigned b = blockIdx.x, t = threadIdx.x;

    if (b < ADD_B) {
        unsigned i = b * 256u + t;
        if (i < ADD_N) {
            // single-use streaming reads: don't pollute L2/L3
            f32x4 va = __builtin_nontemporal_load(nf + i);
            f32x4 vb = __builtin_nontemporal_load(mem + i);
            nm[i] = va + vb;                          // normal store: keep L3-resident
        }
    } else if (b < ADD_B + DM1_B) {
        unsigned i = (b - ADD_B) * 256u + t;
        float e = __builtin_nontemporal_load(et1 + i);
        __builtin_nontemporal_store(ts[i / 20u] - e, dl1 + i);
        __builtin_nontemporal_store((nb1[i] == 0) ? 1.0f : 0.0f, mk1 + i);
    } else if (b < ADD_B + DM1_B + DM2_B) {
        unsigned i = (b - ADD_B - DM1_B) * 256u + t;
        float e = __builtin_nontemporal_load(et2 + i);
        __builtin_nontemporal_store(ts[i / 400u] - e, dl2 + i);
        __builtin_nontemporal_store((nb2[i] == 0) ? 1.0f : 0.0f, mk2 + i);
    } else {
        unsigned i = (b - ADD_B - DM1_B - DM2_B) * 256u + t;   // EF1: 3,522,560 exact
        unsigned row = i / D4, col = i - row * D4;
        unsigned s = (unsigned)ei1[row] * D4 + col;
        __builtin_nontemporal_store(ef[s], ef1o + i);
    }
}
static constexpr unsigned K1_BLOCKS =
    ((100000u * 43u + 255u) / 256u) + (81920u / 256u) + (1638400u / 256u)
    + ((81920u * 43u) / 256u);

// ============ K2: node_mem gathers ============
__global__ __launch_bounds__(256) void k2_nodes(
    const f32x4* __restrict__ nm,
    f32x4* __restrict__ src1, const int* __restrict__ srcn,
    f32x4* __restrict__ nf1o, f32x4* __restrict__ sf2, const int* __restrict__ nb1,
    f32x4* __restrict__ nf2o, const int* __restrict__ nb2)
{
    constexpr unsigned S1_B = (4096u * D4) / 256u;    // 688 exact
    constexpr unsigned N1_B = (81920u * D4) / 256u;   // 13760 exact
    unsigned b = blockIdx.x, t = threadIdx.x;

    if (b < S1_B) {
        unsigned i = b * 256u + t;
        unsigned row = i / D4, col = i - row * D4;
        __builtin_nontemporal_store(nm[(unsigned)srcn[row] * D4 + col], src1 + i);
    } else if (b < S1_B + N1_B) {
        unsigned i = (b - S1_B) * 256u + t;
        unsigned row = i / D4, col = i - row * D4;
        f32x4 v = nm[(unsigned)nb1[row] * D4 + col];
        __builtin_nontemporal_store(v, nf1o + i);
        __builtin_nontemporal_store(v, sf2 + i);
    } else {
        unsigned i = (b - S1_B - N1_B) * 256u + t;    // 70,451,200 exact
        unsigned row = i / D4, col = i - row * D4;
        __builtin_nontemporal_store(nm[(unsigned)nb2[row] * D4 + col], nf2o + i);
    }
}
static constexpr unsigned K2_BLOCKS =
    ((4096u * 43u) / 256u) + ((81920u * 43u) / 256u) + ((1638400u * 43u) / 256u);

// ============ K3: ef2 gather (single pass, contiguous writes) ============
__global__ __launch_bounds__(256) void k3_ef2(
    f32x4* __restrict__ dst, const f32x4* __restrict__ ef, const int* __restrict__ ei2)
{
    unsigned i = blockIdx.x * 256u + threadIdx.x;     // 70,451,200 exact multiple
    unsigned row = i / D4, col = i - row * D4;
    __builtin_nontemporal_store(ef[(unsigned)ei2[row] * D4 + col], dst + i);
}
static constexpr unsigned K3_BLOCKS = (1638400u * 43u) / 256u;

extern "C" void kernel_launch(void* const* d_in, const int* in_sizes, int n_in,
                              void* d_out, int out_size, void* d_ws, size_t ws_size,
                              hipStream_t stream) {
    const float* nf  = (const float*)d_in[0];   // node_feats  [100000,172]
    const float* ef  = (const float*)d_in[1];   // edge_feats  [1000000,172]
    const float* mem = (const float*)d_in[2];   // memory      [100000,172]
    const float* ts  = (const float*)d_in[3];   // timestamps  [4096]
    const float* et1 = (const float*)d_in[4];   // edge_times1 [4096,20]
    const float* et2 = (const float*)d_in[5];   // edge_times2 [81920,20]
    const int* srcn  = (const int*)d_in[6];     // source_nodes [4096]
    const int* nb1   = (const int*)d_in[7];     // neighbors1   [4096,20]
    const int* ei1   = (const int*)d_in[8];     // edge_idxs1   [4096,20]
    const int* nb2   = (const int*)d_in[9];     // neighbors2   [81920,20]
    const int* ei2   = (const int*)d_in[10];    // edge_idxs2   [81920,20]

    constexpr unsigned B = 4096, K = 20, Dd = 172;
    constexpr unsigned BK = B * K;              // 81920

    float* out = (float*)d_out;
    size_t o = 0;
    float* src1 = out + o;  o += (size_t)B * Dd;        // src_feats1
    float* nf1  = out + o;  o += (size_t)BK * Dd;       // neigh_feats1
    float* ef1  = out + o;  o += (size_t)BK * Dd;       // edge_f1
    float* dl1  = out + o;  o += (size_t)BK;            // deltas1
    float* mk1  = out + o;  o += (size_t)BK;            // mask1
    float* sf2  = out + o;  o += (size_t)BK * Dd;       // src_feats2
    float* nf2  = out + o;  o += (size_t)BK * K * Dd;   // neigh_feats2
    float* ef2  = out + o;  o += (size_t)BK * K * Dd;   // edge_f2
    float* dl2  = out + o;  o += (size_t)BK * K;        // deltas2
    float* mk2  = out + o;  o += (size_t)BK * K;        // mask2

    const f32x4* nf4  = (const f32x4*)nf;
    const f32x4* mem4 = (const f32x4*)mem;
    const f32x4* ef4  = (const f32x4*)ef;

    f32x4* nm4 = (f32x4*)d_ws;   // 68.8 MB, harness workspace is ample

    k1_fused<<<K1_BLOCKS, 256, 0, stream>>>(
        nm4, nf4, mem4,
        dl1, mk1, ts, et1, nb1,
        dl2, mk2, et2, nb2,
        (f32x4*)ef1, ef4, ei1);
    k2_nodes<<<K2_BLOCKS, 256, 0, stream>>>(
        nm4,
        (f32x4*)src1, srcn,
        (f32x4*)nf1, (f32x4*)sf2, nb1,
        (f32x4*)nf2, nb2);
    k3_ef2<<<K3_BLOCKS, 256, 0, stream>>>((f32x4*)ef2, ef4, ei2);
}